// Round 7
// baseline (311.878 us; speedup 1.0000x reference)
//
#include <hip/hip_runtime.h>

typedef unsigned int u32;
typedef unsigned char u8;
typedef unsigned long long u64;
typedef int i32x4 __attribute__((ext_vector_type(4)));
typedef int i32x16 __attribute__((ext_vector_type(16)));

// Workspace layout (3.8 MB used):
//   [0, 589824)          Wm[step=tap*8+kc][oc][ic32] i8 (+/-1), 8KB per step
//   [589824, +3211264)   bp bitplanes: bp[(n*256+ch)*49 + (px>>6)], bit px&63
#define WM_OFF 0
#define BP_OFF 589824

// ---------------------------------------------------------------------------
// Kernel 1: prep = pack_w (blocks 0..2303) + bin_bits (blocks 2304..3871).
// ---------------------------------------------------------------------------
__global__ __launch_bounds__(256) void prep(const int* __restrict__ enc,
                                            const float* __restrict__ cb,
                                            char* __restrict__ wm,
                                            const float* __restrict__ x,
                                            u64* __restrict__ bp) {
    int bid = blockIdx.x;
    if (bid < 2304) {
        int idx  = bid * 256 + threadIdx.x;          // 0..589823
        int icin = idx & 31;
        int oc   = (idx >> 5) & 255;
        int step = idx >> 13;                        // 0..71 = tap*8+kc
        int tap  = step >> 3;
        int kc   = step & 7;
        int i = kc * 32 + icin;
        int f = oc * 2304 + i * 9 + tap;             // OIHW flat index
        int j = f / 12;
        int t = f - j * 12;
        float v = cb[enc[j] * 12 + t];
        wm[idx] = v < 0.f ? (char)-1 : (char)1;
    } else {
        int gw   = (bid - 2304) * 4 + (threadIdx.x >> 6);  // 0..6271
        int lane = threadIdx.x & 63;
        const float* xb = x + (size_t)gw * 4096 + lane;
#pragma unroll 1
        for (int k = 0; k < 8; ++k) {
            float v[8];
#pragma unroll
            for (int j = 0; j < 8; ++j) v[j] = xb[k * 512 + j * 64];
            u64 mine = 0;
#pragma unroll
            for (int j = 0; j < 8; ++j) {
                u64 m = __ballot(v[j] < 0.f);
                if (lane == j) mine = m;
            }
            if (lane < 8) bp[(size_t)gw * 64 + k * 8 + lane] = mine;
        }
    }
}

// ---------------------------------------------------------------------------
// Expand one padded row of bitplanes into the swizzled LDS X-tile.
// ---------------------------------------------------------------------------
__device__ __forceinline__ void expand_row(const u64* __restrict__ bp, u8* xr,
                                           int n, int h, int oct, int wseg) {
    bool rowv = (h >= 0) && (h <= 55);
    int w0c = rowv ? ((h * 56) >> 6) : 0;
    int w1c = w0c + 1; if (w1c > 48) w1c = 48;
    const u64* bq = bp + ((size_t)n * 256 + oct * 8) * 49;
    u64 A[8], B[8];
#pragma unroll
    for (int j = 0; j < 8; ++j) A[j] = bq[j * 49 + w0c];
#pragma unroll
    for (int j = 0; j < 8; ++j) B[j] = bq[j * 49 + w1c];
#pragma unroll 1
    for (int k = 0; k < 15; ++k) {
        int wq = wseg + k * 4;
        if (wq >= 58) break;
        u64 out = 0;
        if (rowv && wq >= 1 && wq <= 56) {
            int px  = h * 56 + wq - 1;
            int bit = px & 63;
            bool s2 = (px >> 6) != w0c;
#pragma unroll
            for (int j = 0; j < 8; ++j) {
                u64 wv = s2 ? B[j] : A[j];
                out |= (((wv >> bit) & 1ull) ? 0xFFull : 0x01ull) << (8 * j);
            }
        }
        *(u64*)(xr + wq * 256 + ((oct * 8) ^ ((wq & 15) << 4))) = out;
    }
}

// ---------------------------------------------------------------------------
// Kernel 2: i8 MFMA conv, explicit software pipeline (R7).
// 512 thr, 8 waves = 256 oc x 128 px. R6 post-mortem: full-unroll+setprio
// regressed (115us, MfmaUtil 24) vs R5's explicit depth-2 (98us) -> go FULLY
// explicit: 3-slot A rotation (depth-2, slot=step%3, static names -> no movs),
// 2-slot B ping-pong (depth-1, ds_read k+1 issued before MFMAs of k), B
// prefetch carried ACROSS region boundaries. No setprio. Phases: s-pattern
// P=(2s)%3 -> region use-orders (A0A1A2),(A2A0A1),(A1A2A0), r-independent.
// A-loads walk Wm linearly via uniform base (last 2 overread into bp: ok).
// Split prologue kept; B0 refreshed after mid-barrier (cross-barrier B
// prefetch of row3 is stale for pxg=1 -> dead, reloaded).
// C/D: col=l&31 (px), row=(q&3)+8*(q>>2)+4*(l>>5) (oc)  [HW-verified].
// ---------------------------------------------------------------------------
__global__ __launch_bounds__(512, 4) void conv_mfma(const u64* __restrict__ bp,
                                                    const char* __restrict__ wm,
                                                    float* __restrict__ y) {
    __shared__ __align__(16) u8 xl[61440];   // max K-loop read = 61439: exact
    int t = threadIdx.x;
    // XCD-aware bijective remap (896 % 8 == 0): 4 consecutive n per XCD.
    int lin = blockIdx.x + 28 * blockIdx.y;
    int swb = (lin & 7) * 112 + (lin >> 3);
    int n   = swb / 28;
    int h0  = (swb - n * 28) * 2;

    int oct = t & 31, wseg = (t >> 5) & 3, rr = t >> 7;
    int wave = t >> 6, lane = t & 63;
    int ocg  = wave & 3;
    int pxg  = wave >> 2;
    int col  = lane & 31;
    int half = lane >> 5;
    int ocw  = ocg * 64;
    int aoff = (ocw + col) * 32 + half * 16;
    int h16  = half * 16;

    // Pre-barrier A preload (steps 0,1): global, no LDS dep -> hides under
    // the expansion + barrier.
    const char* wb = wm;
    i32x4 A0a = *(const i32x4*)(wb + aoff);
    i32x4 A0b = *(const i32x4*)(wb + aoff + 1024);
    wb += 8192;
    i32x4 A1a = *(const i32x4*)(wb + aoff);
    i32x4 A1b = *(const i32x4*)(wb + aoff + 1024);
    wb += 8192;                               // -> step 2 (invariant: step k+2)

    if (rr < 3)
        expand_row(bp, xl + rr * 14848, n, h0 + rr - 1, oct, wseg);
    __syncthreads();

    int swA = ((col + 0) & 15) << 4, cbA = (col + 0) * 256;
    int swB = ((col + 1) & 15) << 4, cbB = (col + 1) * 256;
    int swC = ((col + 2) & 15) << 4, cbC = (col + 2) * 256;

    i32x16 acc[2][2] = {};
    i32x4 A2a, A2b, B0a, B0b, B1a, B1b;

    int rowb = pxg * 14848;
    {   // initial B0 = region 0, k=0
        int b0 = rowb + cbA + (h16 ^ swA);
        B0a = *(const i32x4*)&xl[b0];
        B0b = *(const i32x4*)&xl[b0 + 8192];
    }

#define STEP(AUa, AUb, ALa, ALb, BUa, BUb, BLa, BLb, BANL)                    \
    {                                                                          \
        ALa = *(const i32x4*)(wb + aoff);                                      \
        ALb = *(const i32x4*)(wb + aoff + 1024);                               \
        wb += 8192;                                                            \
        int _ba = (BANL);                                                      \
        BLa = *(const i32x4*)&xl[_ba];                                         \
        BLb = *(const i32x4*)&xl[_ba + 8192];                                  \
        acc[0][0] = __builtin_amdgcn_mfma_i32_32x32x32_i8(AUa, BUa, acc[0][0], 0, 0, 0); \
        acc[0][1] = __builtin_amdgcn_mfma_i32_32x32x32_i8(AUa, BUb, acc[0][1], 0, 0, 0); \
        acc[1][0] = __builtin_amdgcn_mfma_i32_32x32x32_i8(AUb, BUa, acc[1][0], 0, 0, 0); \
        acc[1][1] = __builtin_amdgcn_mfma_i32_32x32x32_i8(AUb, BUb, acc[1][1], 0, 0, 0); \
    }

// REGION(X,Y,Z,...): use-order X,Y,Z,X,Y,Z,X,Y; load slot = use-slot of k+2
// (Z,X,Y,...); B ping-pong 0/1; k=7 B-load = next region's ban(0) = NB0.
#define REGION(X, Y, Z, CB, SW, NB0)                                           \
    STEP(X##a, X##b, Z##a, Z##b, B0a, B0b, B1a, B1b, (CB) + ((32  + h16) ^ (SW))) \
    STEP(Y##a, Y##b, X##a, X##b, B1a, B1b, B0a, B0b, (CB) + ((64  + h16) ^ (SW))) \
    STEP(Z##a, Z##b, Y##a, Y##b, B0a, B0b, B1a, B1b, (CB) + ((96  + h16) ^ (SW))) \
    STEP(X##a, X##b, Z##a, Z##b, B1a, B1b, B0a, B0b, (CB) + ((128 + h16) ^ (SW))) \
    STEP(Y##a, Y##b, X##a, X##b, B0a, B0b, B1a, B1b, (CB) + ((160 + h16) ^ (SW))) \
    STEP(Z##a, Z##b, Y##a, Y##b, B1a, B1b, B0a, B0b, (CB) + ((192 + h16) ^ (SW))) \
    STEP(X##a, X##b, Z##a, Z##b, B0a, B0b, B1a, B1b, (CB) + ((224 + h16) ^ (SW))) \
    STEP(Y##a, Y##b, X##a, X##b, B1a, B1b, B0a, B0b, (NB0))

    // Phase 1: r = 0,1 (touch padded rows 0..2 only).
#pragma unroll 1
    for (int r = 0; r < 2; ++r) {
        REGION(A0, A1, A2, rowb + cbA, swA, rowb + cbB + (h16 ^ swB))
        REGION(A2, A0, A1, rowb + cbB, swB, rowb + cbC + (h16 ^ swC))
        REGION(A1, A2, A0, rowb + cbC, swC, rowb + 14848 + cbA + (h16 ^ swA))
        rowb += 14848;
    }

    // Deferred row-3 expansion (A2/B dead here; live = acc + A0,A1).
    if (rr == 3)
        expand_row(bp, xl + 3 * 14848, n, h0 + 2, oct, wseg);
    __syncthreads();

    {   // refresh B0: the cross-barrier prefetch may hold stale row-3 data
        int b0 = rowb + cbA + (h16 ^ swA);
        B0a = *(const i32x4*)&xl[b0];
        B0b = *(const i32x4*)&xl[b0 + 8192];
    }

    // Phase 2: r = 2 (rows pxg+2 in {2,3}); last NB0 is a safe dummy.
    REGION(A0, A1, A2, rowb + cbA, swA, rowb + cbB + (h16 ^ swB))
    REGION(A2, A0, A1, rowb + cbB, swB, rowb + cbC + (h16 ^ swC))
    REGION(A1, A2, A0, rowb + cbC, swC, rowb + cbA + (h16 ^ swA))

#undef REGION
#undef STEP

    int h = h0 + pxg;
    float* yb = y + (size_t)n * 256 * 3136 + (size_t)h * 56;
#pragma unroll
    for (int at = 0; at < 2; ++at) {
#pragma unroll
        for (int bt = 0; bt < 2; ++bt) {
            int w = bt * 32 + col;
            if (w < 56) {
#pragma unroll
                for (int q = 0; q < 16; ++q) {
                    int oc = ocw + at * 32 + (q & 3) + 8 * (q >> 2) + 4 * half;
                    yb[(size_t)oc * 3136 + w] = (float)acc[at][bt][q];
                }
            }
        }
    }
}

extern "C" void kernel_launch(void* const* d_in, const int* in_sizes, int n_in,
                              void* d_out, int out_size, void* d_ws, size_t ws_size,
                              hipStream_t stream) {
    const float* x  = (const float*)d_in[0];
    // d_in[1] (latent weight) unused in the STE forward value.
    const float* cb = (const float*)d_in[2];
    const int* enc  = (const int*)d_in[3];
    float* y        = (float*)d_out;

    char* wmc = (char*)d_ws + WM_OFF;
    u64*  bp  = (u64*)((char*)d_ws + BP_OFF);

    hipLaunchKernelGGL(prep, dim3(3872), dim3(256), 0, stream, enc, cb, wmc, x, bp);
    hipLaunchKernelGGL(conv_mfma, dim3(28, 32), dim3(512), 0, stream, bp, wmc, y);
}

// Round 8
// 276.425 us; speedup vs baseline: 1.1283x; 1.1283x over previous
//
#include <hip/hip_runtime.h>

typedef unsigned int u32;
typedef unsigned char u8;
typedef unsigned long long u64;
typedef int i32x4 __attribute__((ext_vector_type(4)));
typedef int i32x16 __attribute__((ext_vector_type(16)));

// Workspace layout (3.8 MB used):
//   [0, 589824)          Wm[step=tap*8+kc][oc][ic32] i8 (+/-1), 8KB per step
//   [589824, +3211264)   bp bitplanes: bp[(n*256+ch)*49 + (px>>6)], bit px&63
#define WM_OFF 0
#define BP_OFF 589824

// ---------------------------------------------------------------------------
// Kernel 1: prep = pack_w (blocks 0..2303) + bin_bits (blocks 2304..3871).
// ---------------------------------------------------------------------------
__global__ __launch_bounds__(256) void prep(const int* __restrict__ enc,
                                            const float* __restrict__ cb,
                                            char* __restrict__ wm,
                                            const float* __restrict__ x,
                                            u64* __restrict__ bp) {
    int bid = blockIdx.x;
    if (bid < 2304) {
        int idx  = bid * 256 + threadIdx.x;          // 0..589823
        int icin = idx & 31;
        int oc   = (idx >> 5) & 255;
        int step = idx >> 13;                        // 0..71 = tap*8+kc
        int tap  = step >> 3;
        int kc   = step & 7;
        int i = kc * 32 + icin;
        int f = oc * 2304 + i * 9 + tap;             // OIHW flat index
        int j = f / 12;
        int t = f - j * 12;
        float v = cb[enc[j] * 12 + t];
        wm[idx] = v < 0.f ? (char)-1 : (char)1;
    } else {
        int gw   = (bid - 2304) * 4 + (threadIdx.x >> 6);  // 0..6271
        int lane = threadIdx.x & 63;
        const float* xb = x + (size_t)gw * 4096 + lane;
#pragma unroll 1
        for (int k = 0; k < 8; ++k) {
            float v[8];
#pragma unroll
            for (int j = 0; j < 8; ++j) v[j] = xb[k * 512 + j * 64];
            u64 mine = 0;
#pragma unroll
            for (int j = 0; j < 8; ++j) {
                u64 m = __ballot(v[j] < 0.f);
                if (lane == j) mine = m;
            }
            if (lane < 8) bp[(size_t)gw * 64 + k * 8 + lane] = mine;
        }
    }
}

// ---------------------------------------------------------------------------
// Expand one padded row of bitplanes into the swizzled LDS X-tile.
// thread (oct, wseg): channels oct*8..+8, w' = wseg+4k. 16 bp loads (L2-hot),
// 15 u64 LDS writes at [wq*256 + (oct*8 ^ ((wq&15)<<4))].
// ---------------------------------------------------------------------------
__device__ __forceinline__ void expand_row(const u64* __restrict__ bp, u8* xr,
                                           int n, int h, int oct, int wseg) {
    bool rowv = (h >= 0) && (h <= 55);
    int w0c = rowv ? ((h * 56) >> 6) : 0;
    int w1c = w0c + 1; if (w1c > 48) w1c = 48;
    const u64* bq = bp + ((size_t)n * 256 + oct * 8) * 49;
    u64 A[8], B[8];
#pragma unroll
    for (int j = 0; j < 8; ++j) A[j] = bq[j * 49 + w0c];
#pragma unroll
    for (int j = 0; j < 8; ++j) B[j] = bq[j * 49 + w1c];
#pragma unroll 1
    for (int k = 0; k < 15; ++k) {
        int wq = wseg + k * 4;
        if (wq >= 58) break;
        u64 out = 0;
        if (rowv && wq >= 1 && wq <= 56) {
            int px  = h * 56 + wq - 1;
            int bit = px & 63;
            bool s2 = (px >> 6) != w0c;
#pragma unroll
            for (int j = 0; j < 8; ++j) {
                u64 wv = s2 ? B[j] : A[j];
                out |= (((wv >> bit) & 1ull) ? 0xFFull : 0x01ull) << (8 * j);
            }
        }
        *(u64*)(xr + wq * 256 + ((oct * 8) ^ ((wq & 15) << 4))) = out;
    }
}

// ---------------------------------------------------------------------------
// Kernel 2: i8 MFMA conv (R8). 512 thr, 8 waves = 256 oc x 128 px.
// R7 post-mortem: 3 A-slots + carried B spilled (WRITE 160MB). R8 = minimal-
// register zero-mov pipeline:
//   A: SINGLE slot, use-then-reload (WAR keeps order; depth-1, L1-hot linear
//      walk shared by all 8 waves). 8 regs, 0 movs.
//   B: 2-slot even/odd ping-pong, kc unrolled x2; ds_read for k+1 issued
//      before MFMAs of k. 16 regs, 0 movs.
//   Per-region B prime (9 small bubbles) instead of cross-region carry.
// Budget: acc 64 + A 8 + B 16 + addr ~18 ~= 106 < 128 (4 waves/SIMD holds).
// No setprio (R6-null). XCD remap kept (FETCH 18->9MB, R6-proven).
// C/D: col=l&31 (px), row=(q&3)+8*(q>>2)+4*(l>>5) (oc)  [HW-verified].
// ---------------------------------------------------------------------------
__global__ __launch_bounds__(512, 4) void conv_mfma(const u64* __restrict__ bp,
                                                    const char* __restrict__ wm,
                                                    float* __restrict__ y) {
    __shared__ __align__(16) u8 xl[61440];   // max K-loop read = 61439: exact
    int t = threadIdx.x;
    // XCD-aware bijective remap (896 % 8 == 0): 4 consecutive n per XCD.
    int lin = blockIdx.x + 28 * blockIdx.y;
    int swb = (lin & 7) * 112 + (lin >> 3);
    int n   = swb / 28;
    int h0  = (swb - n * 28) * 2;

    int oct = t & 31, wseg = (t >> 5) & 3, rr = t >> 7;
    int wave = t >> 6, lane = t & 63;
    int ocg  = wave & 3;
    int pxg  = wave >> 2;
    int col  = lane & 31;
    int half = lane >> 5;
    int ocw  = ocg * 64;
    int aoff = (ocw + col) * 32 + half * 16;
    int h16  = half * 16;

    // Prime A with step 0 (global, no LDS dep -> hides under expansion+barrier)
    const char* wb = wm;
    i32x4 Aa = *(const i32x4*)(wb + aoff);
    i32x4 Ab = *(const i32x4*)(wb + aoff + 1024);
    wb += 8192;                               // -> step 1

    if (rr < 3)
        expand_row(bp, xl + rr * 14848, n, h0 + rr - 1, oct, wseg);
    __syncthreads();

    int swA = ((col + 0) & 15) << 4, cbA = (col + 0) * 256;
    int swB = ((col + 1) & 15) << 4, cbB = (col + 1) * 256;
    int swC = ((col + 2) & 15) << 4, cbC = (col + 2) * 256;
    int pxb = pxg * 14848;

    i32x16 acc[2][2] = {};
    i32x4 Be0, Be1, Bo0, Bo1;

#define MFMA4(B0, B1)                                                          \
    acc[0][0] = __builtin_amdgcn_mfma_i32_32x32x32_i8(Aa, B0, acc[0][0], 0, 0, 0); \
    acc[0][1] = __builtin_amdgcn_mfma_i32_32x32x32_i8(Aa, B1, acc[0][1], 0, 0, 0); \
    acc[1][0] = __builtin_amdgcn_mfma_i32_32x32x32_i8(Ab, B0, acc[1][0], 0, 0, 0); \
    acc[1][1] = __builtin_amdgcn_mfma_i32_32x32x32_i8(Ab, B1, acc[1][1], 0, 0, 0);

#define ALOAD()                                                                \
    Aa = *(const i32x4*)(wb + aoff);                                           \
    Ab = *(const i32x4*)(wb + aoff + 1024);                                    \
    wb += 8192;

// One region = one (r,s) tap: 8 K-steps, kc unrolled x2 (even/odd ping-pong).
#define REGION(CBASE, SWV)                                                     \
    {                                                                          \
        const int _bb = (CBASE);                                               \
        int _pa = _bb + (h16 ^ (SWV));                                         \
        Be0 = *(const i32x4*)&xl[_pa];                                         \
        Be1 = *(const i32x4*)&xl[_pa + 8192];                                  \
        _Pragma("unroll")                                                      \
        for (int kc2 = 0; kc2 < 4; ++kc2) {                                    \
            int _ko = _bb + ((kc2 * 64 + 32 + h16) ^ (SWV));                   \
            Bo0 = *(const i32x4*)&xl[_ko];                                     \
            Bo1 = *(const i32x4*)&xl[_ko + 8192];                              \
            MFMA4(Be0, Be1)                                                    \
            ALOAD()                                                            \
            if (kc2 < 3) {                                                     \
                int _ke = _bb + ((kc2 * 64 + 64 + h16) ^ (SWV));               \
                Be0 = *(const i32x4*)&xl[_ke];                                 \
                Be1 = *(const i32x4*)&xl[_ke + 8192];                          \
            }                                                                  \
            MFMA4(Bo0, Bo1)                                                    \
            ALOAD()                                                            \
        }                                                                      \
    }

    // Phase 1: r = 0,1 (LDS rows pxg+r in {0,1,2} only; row 3 not yet valid).
    REGION(pxb + cbA, swA)                    // r=0, s=0  (taps 0..)
    REGION(pxb + cbB, swB)
    REGION(pxb + cbC, swC)
    REGION(pxb + 14848 + cbA, swA)            // r=1
    REGION(pxb + 14848 + cbB, swB)
    REGION(pxb + 14848 + cbC, swC)

    // Deferred row-3 expansion (B slots dead here; live = acc + A + addr).
    if (rr == 3)
        expand_row(bp, xl + 3 * 14848, n, h0 + 2, oct, wseg);
    __syncthreads();

    // Phase 2: r = 2 (rows pxg+2 in {2,3}). Final A reloads overread into bp
    // region (wb <= wm + 73*8192 + 9216 < ws end): harmless.
    REGION(pxb + 29696 + cbA, swA)
    REGION(pxb + 29696 + cbB, swB)
    REGION(pxb + 29696 + cbC, swC)

#undef REGION
#undef ALOAD
#undef MFMA4

    int h = h0 + pxg;
    float* yb = y + (size_t)n * 256 * 3136 + (size_t)h * 56;
#pragma unroll
    for (int at = 0; at < 2; ++at) {
#pragma unroll
        for (int bt = 0; bt < 2; ++bt) {
            int w = bt * 32 + col;
            if (w < 56) {
#pragma unroll
                for (int q = 0; q < 16; ++q) {
                    int oc = ocw + at * 32 + (q & 3) + 8 * (q >> 2) + 4 * half;
                    yb[(size_t)oc * 3136 + w] = (float)acc[at][bt][q];
                }
            }
        }
    }
}

extern "C" void kernel_launch(void* const* d_in, const int* in_sizes, int n_in,
                              void* d_out, int out_size, void* d_ws, size_t ws_size,
                              hipStream_t stream) {
    const float* x  = (const float*)d_in[0];
    // d_in[1] (latent weight) unused in the STE forward value.
    const float* cb = (const float*)d_in[2];
    const int* enc  = (const int*)d_in[3];
    float* y        = (float*)d_out;

    char* wmc = (char*)d_ws + WM_OFF;
    u64*  bp  = (u64*)((char*)d_ws + BP_OFF);

    hipLaunchKernelGGL(prep, dim3(3872), dim3(256), 0, stream, enc, cb, wmc, x, bp);
    hipLaunchKernelGGL(conv_mfma, dim3(28, 32), dim3(512), 0, stream, bp, wmc, y);
}

// Round 10
// 264.266 us; speedup vs baseline: 1.1802x; 1.0460x over previous
//
#include <hip/hip_runtime.h>

typedef unsigned int u32;
typedef unsigned char u8;
typedef unsigned long long u64;
typedef int i32x4 __attribute__((ext_vector_type(4)));
typedef int i32x16 __attribute__((ext_vector_type(16)));

// Workspace layout (3.8 MB used):
//   [0, 589824)          Wm[step=tap*8+kc][oc][ic32] i8 (+/-1), 8KB per step
//   [589824, +3211264)   bp bitplanes: bp[(n*256+ch)*49 + (px>>6)], bit px&63
#define WM_OFF 0
#define BP_OFF 589824

// ---------------------------------------------------------------------------
// Kernel 1: prep = pack_w (blocks 0..2303) + bin_bits (blocks 2304..3871).
// ---------------------------------------------------------------------------
__global__ __launch_bounds__(256) void prep(const int* __restrict__ enc,
                                            const float* __restrict__ cb,
                                            char* __restrict__ wm,
                                            const float* __restrict__ x,
                                            u64* __restrict__ bp) {
    int bid = blockIdx.x;
    if (bid < 2304) {
        int idx  = bid * 256 + threadIdx.x;          // 0..589823
        int icin = idx & 31;
        int oc   = (idx >> 5) & 255;
        int step = idx >> 13;                        // 0..71 = tap*8+kc
        int tap  = step >> 3;
        int kc   = step & 7;
        int i = kc * 32 + icin;
        int f = oc * 2304 + i * 9 + tap;             // OIHW flat index
        int j = f / 12;
        int t = f - j * 12;
        float v = cb[enc[j] * 12 + t];
        wm[idx] = v < 0.f ? (char)-1 : (char)1;
    } else {
        int gw   = (bid - 2304) * 4 + (threadIdx.x >> 6);  // 0..6271
        int lane = threadIdx.x & 63;
        const float* xb = x + (size_t)gw * 4096 + lane;
#pragma unroll 1
        for (int k = 0; k < 8; ++k) {
            float v[8];
#pragma unroll
            for (int j = 0; j < 8; ++j) v[j] = xb[k * 512 + j * 64];
            u64 mine = 0;
#pragma unroll
            for (int j = 0; j < 8; ++j) {
                u64 m = __ballot(v[j] < 0.f);
                if (lane == j) mine = m;
            }
            if (lane < 8) bp[(size_t)gw * 64 + k * 8 + lane] = mine;
        }
    }
}

// ---------------------------------------------------------------------------
// Expand one padded row of bitplanes into the swizzled LDS X-tile.
// thread (oct, wseg): channels oct*8..+8, w' = wseg+4k. 16 bp loads (L2-hot),
// 15 u64 LDS writes at [wq*256 + (oct*8 ^ ((wq&15)<<4))].
// ---------------------------------------------------------------------------
__device__ __forceinline__ void expand_row(const u64* __restrict__ bp, u8* xr,
                                           int n, int h, int oct, int wseg) {
    bool rowv = (h >= 0) && (h <= 55);
    int w0c = rowv ? ((h * 56) >> 6) : 0;
    int w1c = w0c + 1; if (w1c > 48) w1c = 48;
    const u64* bq = bp + ((size_t)n * 256 + oct * 8) * 49;
    u64 A[8], B[8];
#pragma unroll
    for (int j = 0; j < 8; ++j) A[j] = bq[j * 49 + w0c];
#pragma unroll
    for (int j = 0; j < 8; ++j) B[j] = bq[j * 49 + w1c];
#pragma unroll 1
    for (int k = 0; k < 15; ++k) {
        int wq = wseg + k * 4;
        if (wq >= 58) break;
        u64 out = 0;
        if (rowv && wq >= 1 && wq <= 56) {
            int px  = h * 56 + wq - 1;
            int bit = px & 63;
            bool s2 = (px >> 6) != w0c;
#pragma unroll
            for (int j = 0; j < 8; ++j) {
                u64 wv = s2 ? B[j] : A[j];
                out |= (((wv >> bit) & 1ull) ? 0xFFull : 0x01ull) << (8 * j);
            }
        }
        *(u64*)(xr + wq * 256 + ((oct * 8) ^ ((wq & 15) << 4))) = out;
    }
}

// ---------------------------------------------------------------------------
// Kernel 2: i8 MFMA conv (R9, resubmitted unchanged after infra failure).
// 512 thr, 8 waves = 256 oc x 128 px.
// R8 post-mortem: deferred row-3 expansion collided with live K-state and the
// 72-step straight-line let the scheduler hoist SGPR-base A-loads -> ~20MB
// scratch (WRITE 124MB). R9:
//  - ALL 4 rows expanded upfront (R5-proven reg-wise): expansion temps die
//    before acc lives; single barrier; no mid-loop expansion.
//  - period-2 K-loop, kc2 UNROLL 1: Ae/Ao + Be/Bo ping-pong with static
//    names -> zero movs, zero cross-step hoisting (loop boundary blocks it),
//    loads for step k+1 issue one full MFMA4 before their use.
//  - slots A 16 + B 16 + acc 64 + addr ~12 < 128 cap (4 waves/SIMD holds).
// kc2=3's dead even-prefetch reads up to xl[61663] -> xl sized 61952.
// No setprio (R6-null). XCD remap kept (FETCH 18->9MB, R6-proven).
// C/D: col=l&31 (px), row=(q&3)+8*(q>>2)+4*(l>>5) (oc)  [HW-verified].
// ---------------------------------------------------------------------------
__global__ __launch_bounds__(512, 4) void conv_mfma(const u64* __restrict__ bp,
                                                    const char* __restrict__ wm,
                                                    float* __restrict__ y) {
    __shared__ __align__(16) u8 xl[61952];   // 4*14848 + dead-prefetch slack
    int t = threadIdx.x;
    // XCD-aware bijective remap (896 % 8 == 0): 4 consecutive n per XCD.
    int lin = blockIdx.x + 28 * blockIdx.y;
    int swb = (lin & 7) * 112 + (lin >> 3);
    int n   = swb / 28;
    int h0  = (swb - n * 28) * 2;

    int oct = t & 31, wseg = (t >> 5) & 3, rr = t >> 7;
    int wave = t >> 6, lane = t & 63;
    int ocg  = wave & 3;
    int pxg  = wave >> 2;
    int col  = lane & 31;
    int half = lane >> 5;
    int ocw  = ocg * 64;
    int aoff = (ocw + col) * 32 + half * 16;
    int h16  = half * 16;

    // Prime A even-slot with step 0 (global, no LDS dep -> hides under the
    // expansion + barrier).
    const char* wb = wm;
    i32x4 Aea = *(const i32x4*)(wb + aoff);
    i32x4 Aeb = *(const i32x4*)(wb + aoff + 1024);
    wb += 8192;                               // -> step 1

    expand_row(bp, xl + rr * 14848, n, h0 + rr - 1, oct, wseg);
    __syncthreads();

    int swA = ((col + 0) & 15) << 4, cbA = (col + 0) * 256;
    int swB = ((col + 1) & 15) << 4, cbB = (col + 1) * 256;
    int swC = ((col + 2) & 15) << 4, cbC = (col + 2) * 256;
    int pxb = pxg * 14848;

    i32x16 acc[2][2] = {};
    i32x4 Aoa, Aob, Be0, Be1, Bo0, Bo1;

#define MFMA4(AA, AB, B0, B1)                                                  \
    acc[0][0] = __builtin_amdgcn_mfma_i32_32x32x32_i8(AA, B0, acc[0][0], 0, 0, 0); \
    acc[0][1] = __builtin_amdgcn_mfma_i32_32x32x32_i8(AA, B1, acc[0][1], 0, 0, 0); \
    acc[1][0] = __builtin_amdgcn_mfma_i32_32x32x32_i8(AB, B0, acc[1][0], 0, 0, 0); \
    acc[1][1] = __builtin_amdgcn_mfma_i32_32x32x32_i8(AB, B1, acc[1][1], 0, 0, 0);

// One region = one (r,s) tap: 8 K-steps as 4 unroll-1 iterations of 2 steps.
// Loop-carried Ae/Be live in fixed regs (no movs); prefetches sit one full
// MFMA4 ahead of their consumer. kc2=3's Be prefetch is dead (in-bounds).
#define REGION(CBASE, SWV)                                                     \
    {                                                                          \
        const int _bb = (CBASE);                                               \
        {                                                                      \
            int _p = _bb + (h16 ^ (SWV));                                      \
            Be0 = *(const i32x4*)&xl[_p];                                      \
            Be1 = *(const i32x4*)&xl[_p + 8192];                               \
        }                                                                      \
        _Pragma("unroll 1")                                                    \
        for (int kc2 = 0; kc2 < 4; ++kc2) {                                    \
            int _kb = kc2 * 64;                                                \
            int _ko = _bb + ((_kb + 32 + h16) ^ (SWV));                        \
            Bo0 = *(const i32x4*)&xl[_ko];                                     \
            Bo1 = *(const i32x4*)&xl[_ko + 8192];                              \
            Aoa = *(const i32x4*)(wb + aoff);                                  \
            Aob = *(const i32x4*)(wb + aoff + 1024);                           \
            wb += 8192;                                                        \
            MFMA4(Aea, Aeb, Be0, Be1)                                          \
            int _ke = _bb + ((_kb + 64 + h16) ^ (SWV));                        \
            Be0 = *(const i32x4*)&xl[_ke];                                     \
            Be1 = *(const i32x4*)&xl[_ke + 8192];                              \
            Aea = *(const i32x4*)(wb + aoff);                                  \
            Aeb = *(const i32x4*)(wb + aoff + 1024);                           \
            wb += 8192;                                                        \
            MFMA4(Aoa, Aob, Bo0, Bo1)                                          \
        }                                                                      \
    }

#pragma unroll 1
    for (int r = 0; r < 3; ++r) {
        int rowb = pxb + r * 14848;
        REGION(rowb + cbA, swA)
        REGION(rowb + cbB, swB)
        REGION(rowb + cbC, swC)
    }
#undef REGION
#undef MFMA4

    // Final Ae prefetch walked to step 72 (8KB into bp region): dead, valid.
    int h = h0 + pxg;
    float* yb = y + (size_t)n * 256 * 3136 + (size_t)h * 56;
#pragma unroll
    for (int at = 0; at < 2; ++at) {
#pragma unroll
        for (int bt = 0; bt < 2; ++bt) {
            int w = bt * 32 + col;
            if (w < 56) {
#pragma unroll
                for (int q = 0; q < 16; ++q) {
                    int oc = ocw + at * 32 + (q & 3) + 8 * (q >> 2) + 4 * half;
                    yb[(size_t)oc * 3136 + w] = (float)acc[at][bt][q];
                }
            }
        }
    }
}

extern "C" void kernel_launch(void* const* d_in, const int* in_sizes, int n_in,
                              void* d_out, int out_size, void* d_ws, size_t ws_size,
                              hipStream_t stream) {
    const float* x  = (const float*)d_in[0];
    // d_in[1] (latent weight) unused in the STE forward value.
    const float* cb = (const float*)d_in[2];
    const int* enc  = (const int*)d_in[3];
    float* y        = (float*)d_out;

    char* wmc = (char*)d_ws + WM_OFF;
    u64*  bp  = (u64*)((char*)d_ws + BP_OFF);

    hipLaunchKernelGGL(prep, dim3(3872), dim3(256), 0, stream, enc, cb, wmc, x, bp);
    hipLaunchKernelGGL(conv_mfma, dim3(28, 32), dim3(512), 0, stream, bp, wmc, y);
}